// Round 8
// baseline (43.877 us; speedup 1.0000x reference)
//
#include <hip/hip_runtime.h>

#define BS  16
#define NN  256
#define HID 128

// XCD-aware swizzle for 1024 blocks: XCD x gets swz in [128x, 128x+128)
// = 2 consecutive batches (intra-kernel L2 locality).
__device__ __forceinline__ int xcd_swz(int bid) {
    return (bid & 7) * 128 + (bid >> 3);
}

// ---------------------------------------------------------------------------
// K1: 4 flat rows per block, 256 threads (thread = (k, q), q in {0,1}).
// x rows via wave-uniform scalar loads; h in LDS (one barrier); ai/aj stored
// TRANSPOSED ([b][k][n]) directly from registers; g = h@W_out.
// ---------------------------------------------------------------------------
__global__ __launch_bounds__(256, 4) void gat_k1(
    const float* __restrict__ x, const float* __restrict__ W_fc,
    const float* __restrict__ b_fc, const float* __restrict__ W_a1,
    const float* __restrict__ b_a1, const float* __restrict__ W_out,
    float* __restrict__ aiT, float* __restrict__ ajT, float* __restrict__ g)
{
    __shared__ __align__(16) float hs[4 * HID];

    const int tid = threadIdx.x;
    const int k   = tid & 127;
    const int q   = tid >> 7;                 // 0..1
    const int swz = xcd_swz(blockIdx.x);
    const int r0  = swz * 4;                  // flat row = b*NN + n0
    const int b   = r0 >> 8;
    const int n0  = r0 & 255;

    // wave-uniform x-row bases -> scalar loads through K$
    const float* x0 = x + __builtin_amdgcn_readfirstlane((r0 + 2 * q) * HID);
    const float* x1 = x0 + HID;

    // ---- phase 1: h rows 2q, 2q+1 (x scalar, weights VGPR) ----
    {
        const float bf = b_fc[k];
        float a0a = bf, a0b = 0.f, a1a = bf, a1b = 0.f;
        #pragma unroll 4
        for (int d0 = 0; d0 < HID; d0 += 8) {
            float w[8];
            #pragma unroll
            for (int t = 0; t < 8; ++t) w[t] = W_fc[(d0 + t) * HID + k];
            a0a += x0[d0+0]*w[0] + x0[d0+1]*w[1] + x0[d0+2]*w[2] + x0[d0+3]*w[3];
            a0b += x0[d0+4]*w[4] + x0[d0+5]*w[5] + x0[d0+6]*w[6] + x0[d0+7]*w[7];
            a1a += x1[d0+0]*w[0] + x1[d0+1]*w[1] + x1[d0+2]*w[2] + x1[d0+3]*w[3];
            a1b += x1[d0+4]*w[4] + x1[d0+5]*w[5] + x1[d0+6]*w[6] + x1[d0+7]*w[7];
        }
        hs[(2 * q + 0) * HID + k] = a0a + a0b;
        hs[(2 * q + 1) * HID + k] = a1a + a1b;
    }
    __syncthreads();

    // ---- phase 2a: q=0 -> aiT rows 0..3; q=1 -> ajT rows 0..3 ----
    {
        const float* Wp  = W_a1 + q * HID * HID;
        const float bias = q ? 0.f : b_a1[k];
        float acc[4][2];
        #pragma unroll
        for (int r = 0; r < 4; ++r) { acc[r][0] = bias; acc[r][1] = 0.f; }
        #pragma unroll 2
        for (int d0 = 0; d0 < HID; d0 += 8) {
            float w[8];
            #pragma unroll
            for (int t = 0; t < 8; ++t) w[t] = Wp[(d0 + t) * HID + k];
            #pragma unroll
            for (int r = 0; r < 4; ++r) {
                const float4 h0 = *(const float4*)&hs[r * HID + d0];
                const float4 h1 = *(const float4*)&hs[r * HID + d0 + 4];
                acc[r][0] += h0.x * w[0] + h0.y * w[1] + h0.z * w[2] + h0.w * w[3];
                acc[r][1] += h1.x * w[4] + h1.y * w[5] + h1.z * w[6] + h1.w * w[7];
            }
        }
        // direct transposed store: (ai|aj)T[b][k][n0..n0+3]
        float* dst = (q ? ajT : aiT) + (b * HID + k) * NN + n0;
        const float4 v = {acc[0][0] + acc[0][1], acc[1][0] + acc[1][1],
                          acc[2][0] + acc[2][1], acc[3][0] + acc[3][1]};
        *(float4*)dst = v;
    }

    // ---- phase 2b: g rows 2q,2q+1 = hs @ W_out ----
    {
        float a0a = 0.f, a0b = 0.f, a1a = 0.f, a1b = 0.f;
        #pragma unroll 4
        for (int d0 = 0; d0 < HID; d0 += 8) {
            float w[8];
            #pragma unroll
            for (int t = 0; t < 8; ++t) w[t] = W_out[(d0 + t) * HID + k];
            const float4 hA0 = *(const float4*)&hs[(2 * q + 0) * HID + d0];
            const float4 hA1 = *(const float4*)&hs[(2 * q + 0) * HID + d0 + 4];
            const float4 hB0 = *(const float4*)&hs[(2 * q + 1) * HID + d0];
            const float4 hB1 = *(const float4*)&hs[(2 * q + 1) * HID + d0 + 4];
            a0a += hA0.x * w[0] + hA0.y * w[1] + hA0.z * w[2] + hA0.w * w[3];
            a0b += hA1.x * w[4] + hA1.y * w[5] + hA1.z * w[6] + hA1.w * w[7];
            a1a += hB0.x * w[0] + hB0.y * w[1] + hB0.z * w[2] + hB0.w * w[3];
            a1b += hB1.x * w[4] + hB1.y * w[5] + hB1.z * w[6] + hB1.w * w[7];
        }
        g[(r0 + 2 * q + 0) * HID + k] = a0a + a0b;
        g[(r0 + 2 * q + 1) * HID + k] = a1a + a1b;
    }
}

// ---------------------------------------------------------------------------
// K2: 4-row i-tile per block, 256 threads (4 waves). Phase A: wave = 4 rows
// x 64-j quarter; aj direct from global (VGPR loads, L2-resident per XCD);
// ai/w2 via SCALAR loads (s_load through K$ — zero LDS traffic); adj
// prefetched. Softmax: 1 row/wave, wave-local. Phase B: g direct from
// global, 2-way j-split + LDS reduce. out = attn@g + b_out.
// ---------------------------------------------------------------------------
__global__ __launch_bounds__(256, 4) void gat_k2(
    const float* __restrict__ aiT, const float* __restrict__ ajT,
    const float* __restrict__ g,  const int* __restrict__ adj,
    const float* __restrict__ w_a2, const float* __restrict__ b_a2,
    const float* __restrict__ b_out, float* __restrict__ out)
{
    __shared__ __align__(16) float ep[4][NN];        // e, then p
    __shared__ __align__(16) float red[2][4][HID];

    const int tid = threadIdx.x;
    const int swz = xcd_swz(blockIdx.x);
    const int b   = swz >> 6;
    const int i0  = (swz & 63) * 4;
    const int wv  = tid >> 6, lane = tid & 63;
    const int j   = wv * 64 + lane;

    // prefetch adj rows (independent of the k-loop)
    int am[4];
    #pragma unroll
    for (int r = 0; r < 4; ++r) am[r] = adj[(b * NN + i0 + r) * NN + j];

    // ---- phase A: e[i0..i0+3][j] — aj VGPR stream, ai/w2 scalar ----
    {
        const float* ajp = ajT + b * HID * NN + j;
        const float* aip = aiT + __builtin_amdgcn_readfirstlane(b * HID * NN + i0);
        float acc[4] = {0.f, 0.f, 0.f, 0.f};
        #pragma unroll 8
        for (int kk = 0; kk < HID; ++kk) {
            const float a   = ajp[kk * NN];
            const float4 s4 = *(const float4*)&aip[kk * NN];   // s_load_dwordx4
            const float wk  = w_a2[kk];                        // s_load
            acc[0] += fmaxf(s4.x + a, 0.f) * wk;
            acc[1] += fmaxf(s4.y + a, 0.f) * wk;
            acc[2] += fmaxf(s4.z + a, 0.f) * wk;
            acc[3] += fmaxf(s4.w + a, 0.f) * wk;
        }
        const float ba2 = b_a2[0];
        #pragma unroll
        for (int r = 0; r < 4; ++r)
            ep[r][j] = am[r] ? acc[r] + ba2 : -1e9f;
    }
    __syncthreads();

    // ---- softmax: wave wv owns row wv ----
    {
        float4 e4 = *(const float4*)&ep[wv][4 * lane];
        float m = fmaxf(fmaxf(e4.x, e4.y), fmaxf(e4.z, e4.w));
        #pragma unroll
        for (int off = 32; off; off >>= 1) m = fmaxf(m, __shfl_xor(m, off));
        const float p0 = __expf(e4.x - m), p1 = __expf(e4.y - m);
        const float p2 = __expf(e4.z - m), p3 = __expf(e4.w - m);
        float s = (p0 + p1) + (p2 + p3);
        #pragma unroll
        for (int off = 32; off; off >>= 1) s += __shfl_xor(s, off);
        const float inv = 1.f / s;
        const float4 pv = {p0 * inv, p1 * inv, p2 * inv, p3 * inv};
        *(float4*)&ep[wv][4 * lane] = pv;
    }
    __syncthreads();

    // ---- phase B: out = attn @ g + b_out, j split in halves ----
    const int k = tid & 127, qh = tid >> 7;   // j in [128qh, 128qh+128)
    {
        float o[4] = {0.f, 0.f, 0.f, 0.f};
        const float* gb = g + (b * NN + qh * 128) * HID + k;
        const int jb = qh * 128;
        #pragma unroll 4
        for (int jq = 0; jq < 128; jq += 4) {
            const float g0 = gb[(jq + 0) * HID];
            const float g1 = gb[(jq + 1) * HID];
            const float g2 = gb[(jq + 2) * HID];
            const float g3 = gb[(jq + 3) * HID];
            const float4 pA = *(const float4*)&ep[0][jb + jq];
            const float4 pB = *(const float4*)&ep[1][jb + jq];
            const float4 pC = *(const float4*)&ep[2][jb + jq];
            const float4 pD = *(const float4*)&ep[3][jb + jq];
            o[0] += pA.x * g0 + pA.y * g1 + pA.z * g2 + pA.w * g3;
            o[1] += pB.x * g0 + pB.y * g1 + pB.z * g2 + pB.w * g3;
            o[2] += pC.x * g0 + pC.y * g1 + pC.z * g2 + pC.w * g3;
            o[3] += pD.x * g0 + pD.y * g1 + pD.z * g2 + pD.w * g3;
        }
        #pragma unroll
        for (int r = 0; r < 4; ++r) red[qh][r][k] = o[r];
    }
    __syncthreads();

    // ---- final reduce: qh handles rows 2qh, 2qh+1 ----
    {
        const float bo = b_out[k];
        #pragma unroll
        for (int r2 = 0; r2 < 2; ++r2) {
            const int r = 2 * qh + r2;
            out[(b * NN + i0 + r) * HID + k] =
                red[0][r][k] + red[1][r][k] + bo;
        }
    }
}

extern "C" void kernel_launch(void* const* d_in, const int* in_sizes, int n_in,
                              void* d_out, int out_size, void* d_ws, size_t ws_size,
                              hipStream_t stream) {
    const float* x     = (const float*)d_in[0];
    const int*   adj   = (const int*)  d_in[1];
    const float* W_fc  = (const float*)d_in[2];
    const float* b_fc  = (const float*)d_in[3];
    const float* W_a1  = (const float*)d_in[4];
    const float* b_a1  = (const float*)d_in[5];
    const float* w_a2  = (const float*)d_in[6];
    const float* b_a2  = (const float*)d_in[7];
    const float* W_out = (const float*)d_in[8];
    const float* b_out = (const float*)d_in[9];
    float* out = (float*)d_out;

    float* ws  = (float*)d_ws;
    float* aiT = ws;                      // aiT[b][k][n], 16*128*256
    float* ajT = ws + BS * NN * HID;      // ajT[b][k][n]
    float* g   = ws + 2 * BS * NN * HID;  // g = h@W_out, [b][n][k]

    gat_k1<<<BS * NN / 4, 256, 0, stream>>>(x, W_fc, b_fc, W_a1, b_a1, W_out,
                                            aiT, ajT, g);
    gat_k2<<<BS * (NN / 4), 256, 0, stream>>>(aiT, ajT, g, adj, w_a2, b_a2,
                                              b_out, out);
}

// Round 9
// 41.411 us; speedup vs baseline: 1.0596x; 1.0596x over previous
//
#include <hip/hip_runtime.h>

#define BS  16
#define NN  256
#define HID 128

// 512 blocks: XCD x gets swz in [64x, 64x+64) = batches 2x, 2x+1.
__device__ __forceinline__ int xcd_swz(int bid) {
    return (bid & 7) * 64 + (bid >> 3);
}

// ---------------------------------------------------------------------------
// K1: 512 blocks, 512 threads, 8 rows/block. Split-K: thread quarters own
// disjoint weight rows -> every weight element read ONCE per block
// (L2 traffic 393 -> 131 MB). Partial sums reduced through LDS.
// ---------------------------------------------------------------------------
__global__ __launch_bounds__(512, 4) void gat_k1(
    const float* __restrict__ x, const float* __restrict__ W_fc,
    const float* __restrict__ b_fc, const float* __restrict__ W_a1,
    const float* __restrict__ b_a1, const float* __restrict__ W_out,
    float* __restrict__ aiT, float* __restrict__ ajT, float* __restrict__ g)
{
    __shared__ __align__(16) float xs[8][HID];           // 4KB
    __shared__ __align__(16) float hs[8][HID];           // 4KB
    __shared__ __align__(16) float red[4][8][HID];       // 16KB

    const int tid = threadIdx.x;
    const int k   = tid & 127;
    const int q   = tid >> 7;                 // 0..3
    const int swz = xcd_swz(blockIdx.x);
    const int r0  = swz * 8;                  // flat row = b*NN + n0
    const int b   = r0 >> 8;
    const int n0  = r0 & 255;

    for (int t = tid; t < 8 * HID; t += 512)
        xs[t >> 7][t & 127] = x[r0 * HID + t];
    __syncthreads();

    // ---- phase 1: h partials, split-K quarter d in [32q, 32q+32) ----
    {
        float acc[8] = {0,0,0,0,0,0,0,0};
        const int dq = 32 * q;
        #pragma unroll 2
        for (int d = 0; d < 32; d += 4) {
            float w[4];
            #pragma unroll
            for (int t = 0; t < 4; ++t) w[t] = W_fc[(dq + d + t) * HID + k];
            #pragma unroll
            for (int r = 0; r < 8; ++r) {
                const float4 xv = *(const float4*)&xs[r][dq + d];
                acc[r] += xv.x * w[0] + xv.y * w[1] + xv.z * w[2] + xv.w * w[3];
            }
        }
        #pragma unroll
        for (int r = 0; r < 8; ++r) red[q][r][k] = acc[r];
    }
    __syncthreads();

    // ---- reduce h: thread (k,q) -> rows 2q, 2q+1 ----
    {
        const float bf = b_fc[k];
        #pragma unroll
        for (int r2 = 0; r2 < 2; ++r2) {
            const int r = 2 * q + r2;
            hs[r][k] = (red[0][r][k] + red[1][r][k])
                     + (red[2][r][k] + red[3][r][k]) + bf;
        }
    }
    __syncthreads();

    // ---- phase 2a: q0/q1 -> ai d-halves; q2/q3 -> aj d-halves ----
    {
        const int is_aj = q >> 1;
        const int half  = q & 1;
        const float* Wp = W_a1 + (is_aj * HID + half * 64) * HID;
        float acc[8] = {0,0,0,0,0,0,0,0};
        const int hb = half * 64;
        #pragma unroll 2
        for (int d = 0; d < 64; d += 4) {
            float w[4];
            #pragma unroll
            for (int t = 0; t < 4; ++t) w[t] = Wp[(d + t) * HID + k];
            #pragma unroll
            for (int r = 0; r < 8; ++r) {
                const float4 hv = *(const float4*)&hs[r][hb + d];
                acc[r] += hv.x * w[0] + hv.y * w[1] + hv.z * w[2] + hv.w * w[3];
            }
        }
        #pragma unroll
        for (int r = 0; r < 8; ++r) red[q][r][k] = acc[r];
    }
    __syncthreads();

    // ---- reduce + transposed store: q selects (ai|aj, row-quad) ----
    {
        const int is_aj = q >> 1;
        const int rb4   = (q & 1) * 4;
        const float bias = is_aj ? 0.f : b_a1[k];
        const int p0 = 2 * is_aj, p1 = 2 * is_aj + 1;
        float4 v;
        v.x = red[p0][rb4 + 0][k] + red[p1][rb4 + 0][k] + bias;
        v.y = red[p0][rb4 + 1][k] + red[p1][rb4 + 1][k] + bias;
        v.z = red[p0][rb4 + 2][k] + red[p1][rb4 + 2][k] + bias;
        v.w = red[p0][rb4 + 3][k] + red[p1][rb4 + 3][k] + bias;
        float* dst = (is_aj ? ajT : aiT) + (b * HID + k) * NN + n0 + rb4;
        *(float4*)dst = v;
    }
    __syncthreads();   // red free again

    // ---- phase 2b: g partials, split-K quarters ----
    {
        float acc[8] = {0,0,0,0,0,0,0,0};
        const int dq = 32 * q;
        #pragma unroll 2
        for (int d = 0; d < 32; d += 4) {
            float w[4];
            #pragma unroll
            for (int t = 0; t < 4; ++t) w[t] = W_out[(dq + d + t) * HID + k];
            #pragma unroll
            for (int r = 0; r < 8; ++r) {
                const float4 hv = *(const float4*)&hs[r][dq + d];
                acc[r] += hv.x * w[0] + hv.y * w[1] + hv.z * w[2] + hv.w * w[3];
            }
        }
        #pragma unroll
        for (int r = 0; r < 8; ++r) red[q][r][k] = acc[r];
    }
    __syncthreads();

    // ---- reduce g: thread (k,q) -> rows 2q, 2q+1 ----
    {
        #pragma unroll
        for (int r2 = 0; r2 < 2; ++r2) {
            const int r = 2 * q + r2;
            g[(r0 + r) * HID + k] = (red[0][r][k] + red[1][r][k])
                                  + (red[2][r][k] + red[3][r][k]);
        }
    }
}

// ---------------------------------------------------------------------------
// K2: 512 blocks, 512 threads, 8-row i-tile (ajT/g slabs amortized 2x).
// Phase A: wave = 32 j-cols x 2 row-groups (lane>>5); aj loads dedup via
// intra-wave same-address coalescing; ai from LDS [kk][8] (b128 2-way
// broadcast). Softmax 1 row/wave. Phase B: j-quartered, g read once per
// block, LDS reduce. out = attn@g + b_out.
// ---------------------------------------------------------------------------
__global__ __launch_bounds__(512, 4) void gat_k2(
    const float* __restrict__ aiT, const float* __restrict__ ajT,
    const float* __restrict__ g,  const int* __restrict__ adj,
    const float* __restrict__ w_a2, const float* __restrict__ b_a2,
    const float* __restrict__ b_out, float* __restrict__ out)
{
    __shared__ __align__(16) float aiw[HID][8];          // 4KB, [k][row]
    __shared__ __align__(16) float w2s[HID];
    __shared__ __align__(16) float ep[8][NN];            // 8KB
    __shared__ __align__(16) float red[4][8][HID];       // 16KB

    const int tid = threadIdx.x;
    const int swz = xcd_swz(blockIdx.x);
    const int b   = swz >> 5;
    const int i0  = (swz & 31) * 8;
    const int wv  = tid >> 6, lane = tid & 63;

    for (int t = tid; t < HID * 8; t += 512) {
        const int kk = t >> 3, r = t & 7;
        aiw[kk][r] = aiT[(b * HID + kk) * NN + i0 + r];
    }
    if (tid < HID) w2s[tid] = w_a2[tid];
    __syncthreads();

    // ---- phase A: e[8 rows][j], wave covers 32 j x all 8 rows ----
    const int jj = 32 * wv + (lane & 31);
    const int rg = lane >> 5;                 // rows 4rg .. 4rg+3
    {
        int am[4];
        #pragma unroll
        for (int r = 0; r < 4; ++r)
            am[r] = adj[(b * NN + i0 + 4 * rg + r) * NN + jj];

        const float* ajp = ajT + b * HID * NN + jj;
        float acc[4] = {0.f, 0.f, 0.f, 0.f};
        #pragma unroll 8
        for (int kk = 0; kk < HID; ++kk) {
            const float a   = ajp[kk * NN];
            const float4 f4 = *(const float4*)&aiw[kk][4 * rg];
            const float wk  = w2s[kk];
            acc[0] += fmaxf(f4.x + a, 0.f) * wk;
            acc[1] += fmaxf(f4.y + a, 0.f) * wk;
            acc[2] += fmaxf(f4.z + a, 0.f) * wk;
            acc[3] += fmaxf(f4.w + a, 0.f) * wk;
        }
        const float ba2 = b_a2[0];
        #pragma unroll
        for (int r = 0; r < 4; ++r)
            ep[4 * rg + r][jj] = am[r] ? acc[r] + ba2 : -1e9f;
    }
    __syncthreads();

    // ---- softmax: wave wv owns row wv ----
    {
        float4 e4 = *(const float4*)&ep[wv][4 * lane];
        float m = fmaxf(fmaxf(e4.x, e4.y), fmaxf(e4.z, e4.w));
        #pragma unroll
        for (int off = 32; off; off >>= 1) m = fmaxf(m, __shfl_xor(m, off));
        const float p0 = __expf(e4.x - m), p1 = __expf(e4.y - m);
        const float p2 = __expf(e4.z - m), p3 = __expf(e4.w - m);
        float s = (p0 + p1) + (p2 + p3);
        #pragma unroll
        for (int off = 32; off; off >>= 1) s += __shfl_xor(s, off);
        const float inv = 1.f / s;
        const float4 pv = {p0 * inv, p1 * inv, p2 * inv, p3 * inv};
        *(float4*)&ep[wv][4 * lane] = pv;
    }
    __syncthreads();

    // ---- phase B: out = attn @ g, j in quarters ----
    const int k = tid & 127, qh = tid >> 7;   // j in [64qh, 64qh+64)
    {
        float o[8] = {0,0,0,0,0,0,0,0};
        const float* gb = g + (b * NN + qh * 64) * HID + k;
        const int jb = qh * 64;
        #pragma unroll 2
        for (int jq = 0; jq < 64; jq += 4) {
            const float g0 = gb[(jq + 0) * HID];
            const float g1 = gb[(jq + 1) * HID];
            const float g2 = gb[(jq + 2) * HID];
            const float g3 = gb[(jq + 3) * HID];
            #pragma unroll
            for (int r = 0; r < 8; ++r) {
                const float4 pv = *(const float4*)&ep[r][jb + jq];
                o[r] += pv.x * g0 + pv.y * g1 + pv.z * g2 + pv.w * g3;
            }
        }
        #pragma unroll
        for (int r = 0; r < 8; ++r) red[qh][r][k] = o[r];
    }
    __syncthreads();

    // ---- final reduce: thread (k,qh) -> rows 2qh, 2qh+1 ----
    {
        const float bo = b_out[k];
        #pragma unroll
        for (int r2 = 0; r2 < 2; ++r2) {
            const int r = 2 * qh + r2;
            out[(b * NN + i0 + r) * HID + k] =
                (red[0][r][k] + red[1][r][k]) +
                (red[2][r][k] + red[3][r][k]) + bo;
        }
    }
}

extern "C" void kernel_launch(void* const* d_in, const int* in_sizes, int n_in,
                              void* d_out, int out_size, void* d_ws, size_t ws_size,
                              hipStream_t stream) {
    const float* x     = (const float*)d_in[0];
    const int*   adj   = (const int*)  d_in[1];
    const float* W_fc  = (const float*)d_in[2];
    const float* b_fc  = (const float*)d_in[3];
    const float* W_a1  = (const float*)d_in[4];
    const float* b_a1  = (const float*)d_in[5];
    const float* w_a2  = (const float*)d_in[6];
    const float* b_a2  = (const float*)d_in[7];
    const float* W_out = (const float*)d_in[8];
    const float* b_out = (const float*)d_in[9];
    float* out = (float*)d_out;

    float* ws  = (float*)d_ws;
    float* aiT = ws;                      // aiT[b][k][n]
    float* ajT = ws + BS * NN * HID;      // ajT[b][k][n]
    float* g   = ws + 2 * BS * NN * HID;  // g = h@W_out, [b][n][k]

    gat_k1<<<BS * NN / 8, 512, 0, stream>>>(x, W_fc, b_fc, W_a1, b_a1, W_out,
                                            aiT, ajT, g);
    gat_k2<<<BS * (NN / 8), 512, 0, stream>>>(aiT, ajT, g, adj, w_a2, b_a2,
                                              b_out, out);
}